// Round 18
// baseline (123.099 us; speedup 1.0000x reference)
//
#include <hip/hip_runtime.h>
#include <hip/hip_fp16.h>

typedef _Float16 f16x8 __attribute__((ext_vector_type(8)));
typedef __fp16 fp16x2 __attribute__((ext_vector_type(2)));   // cvt_pkrtz return type
typedef float f32x4 __attribute__((ext_vector_type(4)));

namespace {

constexpr int B = 2, C = 256, T = 2304, F = 1024, NH = 8, HD = 32;
constexpr int BH = B * NH;           // 16
constexpr int NCHUNK = 4;
constexpr int CHUNK = T / NCHUNK;    // 576
constexpr float C2 = 0.17677669529663687f * 1.4426950408889634f;  // scale*log2(e)
constexpr float INV_N = 1.0f / (float)(C * T);

// f16 weight block sizes (flat elements)
constexpr size_t N_WQKV = (size_t)3 * C * C;   // 196608
constexpr size_t N_WO   = (size_t)C * C;       // 65536
constexpr size_t N_W1   = (size_t)F * C;       // 262144
constexpr size_t N_W2   = (size_t)C * F;       // 262144
constexpr size_t N_WALL = N_WQKV + N_WO + N_W1 + N_W2;

// workspace layout (bytes)
constexpr size_t OFF_QKV  = 0;                                // f16 [B][3C][T]
constexpr size_t SZ_QKV   = (size_t)B * 3 * C * T * 2;
constexpr size_t OFF_AO   = OFF_QKV + SZ_QKV;                 // f16 [B][C][T]
constexpr size_t SZ_AO    = (size_t)B * C * T * 2;
constexpr size_t OFF_X1   = OFF_AO + SZ_AO;                   // f16 [B][C][T] (raw, pre-GN1)
constexpr size_t SZ_X1    = (size_t)B * C * T * 2;
// union region: attention partials, later reused as FFN hidden h16
constexpr size_t OFF_PART = OFF_X1 + SZ_X1;
constexpr size_t SZ_OP    = (size_t)NCHUNK * BH * HD * T * 2; // f16 chunk-normalized O
constexpr size_t SZ_MP    = (size_t)NCHUNK * BH * T * 4;      // f32
constexpr size_t OFF_OP   = OFF_PART;
constexpr size_t OFF_MP   = OFF_OP + SZ_OP;
constexpr size_t OFF_LP   = OFF_MP + SZ_MP;
constexpr size_t SZ_H16   = (size_t)B * F * T * 2;
constexpr size_t SZ_PART  = SZ_OP + 2 * SZ_MP;
constexpr size_t SZ_UNION = SZ_PART > SZ_H16 ? SZ_PART : SZ_H16;
constexpr size_t OFF_H16  = OFF_PART;
constexpr size_t OFF_W16  = OFF_PART + SZ_UNION;              // f16 weights (qkv|wo|w1|w2)
constexpr size_t OFF_BQKV = OFF_W16 + N_WALL * 2;             // f32 [768]
constexpr size_t OFF_STATS = OFF_BQKV + (size_t)3 * C * 4;    // f32 [8]

} // namespace

// Convert all weights fp32 -> f16 into one flat buffer (float4 vectorized);
// concat qkv bias; zero stats.
__global__ __launch_bounds__(256)
void convert_weights(const float* __restrict__ wq, const float* __restrict__ wk,
                     const float* __restrict__ wv, const float* __restrict__ wo,
                     const float* __restrict__ w1, const float* __restrict__ w2,
                     const float* __restrict__ bq, const float* __restrict__ bk,
                     const float* __restrict__ bv,
                     _Float16* __restrict__ w16, float* __restrict__ bqkv,
                     float* __restrict__ stats)
{
  const size_t tid = (size_t)blockIdx.x * 256 + threadIdx.x;
  if (tid < 8) stats[tid] = 0.f;
  if (tid < 3 * C)
    bqkv[tid] = tid < C ? bq[tid] : (tid < 2 * C ? bk[tid - C] : bv[tid - 2 * C]);
  for (size_t i4 = tid; i4 < N_WALL / 4; i4 += (size_t)gridDim.x * 256) {
    const size_t e = i4 * 4;
    const float* src;
    if      (e < 65536)  src = wq + e;
    else if (e < 131072) src = wk + (e - 65536);
    else if (e < 196608) src = wv + (e - 131072);
    else if (e < 262144) src = wo + (e - 196608);
    else if (e < 524288) src = w1 + (e - 262144);
    else                 src = w2 + (e - 524288);
    const float4 v = *(const float4*)src;
    union { _Float16 h[4]; uint2 u; } pk;
    pk.h[0] = (_Float16)v.x; pk.h[1] = (_Float16)v.y;
    pk.h[2] = (_Float16)v.z; pk.h[3] = (_Float16)v.w;
    *(uint2*)(w16 + e) = pk.u;
  }
}

// out[b][co][t] = act( W[co][:] . X[b][:][t] + bias[co] (+ res') )
// 64x64 tile, 4 waves, each wave a 32x32 sub-tile via 2x2 mfma 16x16x32.
// Register prefetch of BOTH X and A-fragments + double-buffered LDS +
// ONE barrier per 32-K step. Packed f32->f16 staging conversion.
// Prefetch guarded by uniform branch (no clamped redundant last-step loads).
template<bool RELU, bool RES, bool GNIN, bool GNRES, bool STATS,
         typename InT, typename ResT, typename OutT>
__global__ __launch_bounds__(256)
void gemm_mfma(const _Float16* __restrict__ W, const InT* __restrict__ X,
               const float* __restrict__ bias, const ResT* __restrict__ res,
               OutT* __restrict__ out, int CO, int K,
               const float* __restrict__ stats_in,
               const float* __restrict__ gamma, const float* __restrict__ beta,
               float* __restrict__ stats_out)
{
  const int b   = blockIdx.z;
  const int co0 = blockIdx.y * 64;
  const int t0  = blockIdx.x * 64;
  const int tid = threadIdx.x;
  const int wid = tid >> 6, lane = tid & 63;
  const int g = lane >> 4, lo = lane & 15;
  const int wm = wid & 1, wn = wid >> 1;

  __shared__ f16x8 xs[2][4][64];   // double-buffered [k/8][t] 32-k step
  __shared__ float gs[256], bs[256];
  __shared__ float red[8];

  float mu = 0.f, rsig = 0.f;
  if (GNIN || GNRES) {
    const float s1 = stats_in[b * 2], s2 = stats_in[b * 2 + 1];
    mu = s1 * INV_N;
    rsig = rsqrtf(s2 * INV_N - mu * mu + 1e-5f);
  }
  if (GNIN) { gs[tid] = gamma[tid]; bs[tid] = beta[tid]; }

  const f32x4 z4 = {0.f, 0.f, 0.f, 0.f};
  f32x4 acc00 = z4, acc01 = z4, acc10 = z4, acc11 = z4;

  const int st = tid & 63;   // staged t within tile
  const int kp = tid >> 6;   // staged k/8 within step
  const InT* Xp = X + (size_t)b * K * T + t0 + st;
  const _Float16* Wp = W + (size_t)(co0 + wm * 32 + lo) * K + 8 * g;

  // prologue: step-0 X floats and A-frags into regs
  float xr[8];
#pragma unroll
  for (int j = 0; j < 8; ++j) xr[j] = (float)Xp[(size_t)(kp * 8 + j) * T];
  f16x8 afc0 = *(const f16x8*)(Wp);
  f16x8 afc1 = *(const f16x8*)(Wp + (size_t)16 * K);

  __syncthreads();   // gs/bs visible before first staged write uses them

  int it = 0;
  for (int k0 = 0; k0 < K; k0 += 32, ++it) {
    const int buf = it & 1;
    // write current staged regs to LDS[buf] (packed cvt)
    union { fp16x2 h2[4]; f16x8 v8; } u;
#pragma unroll
    for (int j2 = 0; j2 < 4; ++j2) {
      float v0 = xr[2 * j2], v1 = xr[2 * j2 + 1];
      if (GNIN) {
        const int k = k0 + kp * 8 + 2 * j2;
        v0 = (v0 - mu) * rsig * gs[k] + bs[k];
        v1 = (v1 - mu) * rsig * gs[k + 1] + bs[k + 1];
      }
      u.h2[j2] = __builtin_amdgcn_cvt_pkrtz(v0, v1);
    }
    xs[buf][kp][st] = u.v8;

    // issue next step's X and A loads (uniform guard; none on last iter)
    f16x8 afn0, afn1;
    const bool more = (k0 + 32 < K);
    if (more) {
      const int k1 = k0 + 32;
#pragma unroll
      for (int j = 0; j < 8; ++j) xr[j] = (float)Xp[(size_t)(k1 + kp * 8 + j) * T];
      afn0 = *(const f16x8*)(Wp + (size_t)k1);
      afn1 = *(const f16x8*)(Wp + (size_t)16 * K + k1);
    }

    __syncthreads();   // staging of LDS[buf] complete for all waves

    const f16x8 bf0 = xs[buf][g][wn * 32 + lo];
    const f16x8 bf1 = xs[buf][g][wn * 32 + 16 + lo];
    acc00 = __builtin_amdgcn_mfma_f32_16x16x32_f16(afc0, bf0, acc00, 0, 0, 0);
    acc01 = __builtin_amdgcn_mfma_f32_16x16x32_f16(afc0, bf1, acc01, 0, 0, 0);
    acc10 = __builtin_amdgcn_mfma_f32_16x16x32_f16(afc1, bf0, acc10, 0, 0, 0);
    acc11 = __builtin_amdgcn_mfma_f32_16x16x32_f16(afc1, bf1, acc11, 0, 0, 0);

    if (more) { afc0 = afn0; afc1 = afn1; }
  }

  float s = 0.f, ss = 0.f;
  const size_t obase = ((size_t)b * CO + co0 + wm * 32) * T + t0 + wn * 32 + lo;
  const ResT* resb = res + obase;   // valid only if RES
  OutT* outb = out + obase;
  const f32x4 accs[2][2] = {{acc00, acc01}, {acc10, acc11}};
#pragma unroll
  for (int mi = 0; mi < 2; ++mi) {
#pragma unroll
    for (int r = 0; r < 4; ++r) {
      const int row = mi * 16 + 4 * g + r;
      const int co = co0 + wm * 32 + row;
      const float bi = bias[co];
      float gm = 0.f, bt = 0.f;
      if (GNRES) { gm = gamma[co]; bt = beta[co]; }
#pragma unroll
      for (int ni = 0; ni < 2; ++ni) {
        float v = accs[mi][ni][r] + bi;
        if (RES) {
          float rv = (float)resb[(size_t)row * T + ni * 16];
          if (GNRES) rv = (rv - mu) * rsig * gm + bt;
          v += rv;
        }
        if (RELU) v = fmaxf(v, 0.f);
        outb[(size_t)row * T + ni * 16] = (OutT)v;
        if (STATS) { s += v; ss = fmaf(v, v, ss); }
      }
    }
  }

  if (STATS) {
#pragma unroll
    for (int off = 32; off > 0; off >>= 1) {
      s  += __shfl_down(s, off);
      ss += __shfl_down(ss, off);
    }
    if (lane == 0) { red[wid] = s; red[4 + wid] = ss; }
    __syncthreads();
    if (tid == 0) {
      atomicAdd(&stats_out[b * 2],     red[0] + red[1] + red[2] + red[3]);
      atomicAdd(&stats_out[b * 2 + 1], red[4] + red[5] + red[6] + red[7]);
    }
  }
}

// Flash-attention partials over one key chunk (MFMA, exp2-domain softmax).
// 8 waves / 128 queries per block; double-buffered K/V LDS staging, single
// barrier per iter; defer-max (bit-exact skip); packed P conversion; last
// iteration peeled (no clamped redundant loads). Q pre-scaled.
__global__ __launch_bounds__(512)
void attn_mfma(const _Float16* __restrict__ qkv, _Float16* __restrict__ opart,
               float* __restrict__ mpart, float* __restrict__ lpart)
{
  const int tid  = threadIdx.x;
  const int wid  = tid >> 6;       // 0..7
  const int lane = tid & 63;
  const int g    = lane >> 4;
  const int lo   = lane & 15;
  const int chunk = blockIdx.y;
  const int bh   = blockIdx.z;
  const int b    = bh >> 3, h = bh & 7;
  const int tq   = blockIdx.x * 128 + wid * 16 + lo;
  const size_t qb = ((size_t)b * 3 * C + h * HD) * T;
  const size_t kb = qb + (size_t)C * T;
  const size_t vb = qb + (size_t)2 * C * T;

  __shared__ _Float16 kt[2][64][36];   // [buf][tk][d] transposed K tile
  __shared__ _Float16 vt[2][32][72];   // [buf][d][tk] V tile
  __shared__ _Float16 pl[8][16][72];   // per-wave P: [tq][tk]

  // staging thread roles (512 threads)
  const int t   = tid & 63;    // K stage: key index
  const int dp  = tid >> 6;    // K stage: d-quad group (0..7)
  const int dv  = tid >> 4;    // V stage: d (0..31)
  const int seg = tid & 15;    // V stage: 4-key segment

  // Q fragment pre-scaled by C2 (f32 multiply, then f16)
  f16x8 qf;
#pragma unroll
  for (int j = 0; j < 8; ++j)
    qf[j] = (_Float16)((float)qkv[qb + (size_t)(8 * g + j) * T + tq] * C2);

  const f32x4 zero4 = {0.f, 0.f, 0.f, 0.f};
  f32x4 oa[2] = {zero4, zero4};
  float m = -1e30f, l = 0.f;

  constexpr int NIT = CHUNK / 64;

  // shared compute body (reads LDS[buf], updates m/l/oa)
  auto compute = [&](int buf) {
    f32x4 s4[4];
#pragma unroll
    for (int mt = 0; mt < 4; ++mt) {
      union { f16x8 v; uint2 u[2]; } kf;
      const _Float16* kr = &kt[buf][mt * 16 + lo][8 * g];
      kf.u[0] = *(const uint2*)(kr);
      kf.u[1] = *(const uint2*)(kr + 4);
      s4[mt] = __builtin_amdgcn_mfma_f32_16x16x32_f16(kf.v, qf, zero4, 0, 0, 0);
    }
    float rmax = -1e30f;
#pragma unroll
    for (int mt = 0; mt < 4; ++mt) {
      const float m01 = fmaxf(s4[mt][0], s4[mt][1]);
      const float m23 = fmaxf(s4[mt][2], s4[mt][3]);
      rmax = fmaxf(rmax, fmaxf(m01, m23));
    }
    rmax = fmaxf(rmax, __shfl_xor(rmax, 16));
    rmax = fmaxf(rmax, __shfl_xor(rmax, 32));
    // defer-max: when rmax <= m, fsc == 1 exactly -> skip rescale (bit-exact)
    if (!__all(rmax <= m)) {
      const float mn = fmaxf(m, rmax);
      const float fsc = __builtin_amdgcn_exp2f(m - mn);
      m = mn;
      l *= fsc;
#pragma unroll
      for (int dt = 0; dt < 2; ++dt)
#pragma unroll
        for (int r = 0; r < 4; ++r) oa[dt][r] *= fsc;
    }
    float p[4][4];
    float psum = 0.f;
#pragma unroll
    for (int mt = 0; mt < 4; ++mt)
#pragma unroll
      for (int r = 0; r < 4; ++r) {
        p[mt][r] = __builtin_amdgcn_exp2f(s4[mt][r] - m);
        psum += p[mt][r];
      }
    psum += __shfl_xor(psum, 16);
    psum += __shfl_xor(psum, 32);
    l += psum;

    // P -> per-wave LDS (packed cvt, b64 writes), then read B-frags (b128)
#pragma unroll
    for (int mt = 0; mt < 4; ++mt) {
      union { fp16x2 h2[2]; uint2 u2; } pw;
      pw.h2[0] = __builtin_amdgcn_cvt_pkrtz(p[mt][0], p[mt][1]);
      pw.h2[1] = __builtin_amdgcn_cvt_pkrtz(p[mt][2], p[mt][3]);
      *(uint2*)&pl[wid][lo][16 * mt + 4 * g] = pw.u2;
    }
#pragma unroll
    for (int c2 = 0; c2 < 2; ++c2) {
      const f16x8 pbv = *(const f16x8*)&pl[wid][lo][c2 * 32 + 8 * g];
#pragma unroll
      for (int dt = 0; dt < 2; ++dt) {
        const f16x8 vf = *(const f16x8*)&vt[buf][dt * 16 + lo][c2 * 32 + 8 * g];
        oa[dt] = __builtin_amdgcn_mfma_f32_16x16x32_f16(vf, pbv, oa[dt], 0, 0, 0);
      }
    }
  };

  // prologue: load tile 0 into regs
  ushort ka[4];
  uint2  va;
  {
    const int tk0 = chunk * CHUNK;
#pragma unroll
    for (int dd = 0; dd < 4; ++dd)
      ka[dd] = *(const ushort*)(qkv + kb + (size_t)(dp * 4 + dd) * T + tk0 + t);
    va = *(const uint2*)(qkv + vb + (size_t)dv * T + tk0 + seg * 4);
  }

  for (int it = 0; it < NIT - 1; ++it) {
    const int buf = it & 1;

    // write current staged regs to LDS[buf]
    *(uint*)&kt[buf][t][dp * 4]     = (uint)ka[0] | ((uint)ka[1] << 16);
    *(uint*)&kt[buf][t][dp * 4 + 2] = (uint)ka[2] | ((uint)ka[3] << 16);
    *(uint2*)&vt[buf][dv][seg * 4] = va;

    // issue next tile's global loads (no clamp -- loop bound guarantees valid)
    const int tkn = chunk * CHUNK + (it + 1) * 64;
    ushort ka2[4];
    uint2  va2;
#pragma unroll
    for (int dd = 0; dd < 4; ++dd)
      ka2[dd] = *(const ushort*)(qkv + kb + (size_t)(dp * 4 + dd) * T + tkn + t);
    va2 = *(const uint2*)(qkv + vb + (size_t)dv * T + tkn + seg * 4);

    __syncthreads();   // staging of LDS[buf] complete for all waves
    compute(buf);

#pragma unroll
    for (int dd = 0; dd < 4; ++dd) ka[dd] = ka2[dd];
    va = va2;
  }

  // final iteration (no prefetch)
  {
    const int buf = (NIT - 1) & 1;
    *(uint*)&kt[buf][t][dp * 4]     = (uint)ka[0] | ((uint)ka[1] << 16);
    *(uint*)&kt[buf][t][dp * 4 + 2] = (uint)ka[2] | ((uint)ka[3] << 16);
    *(uint2*)&vt[buf][dv][seg * 4] = va;
    __syncthreads();
    compute(buf);
  }

  // epilogue: store chunk-normalized O (f16) + m,l
  const float invL = 1.f / l;
  const size_t ob = (size_t)(chunk * BH + bh) * HD * T;
#pragma unroll
  for (int dt = 0; dt < 2; ++dt)
#pragma unroll
    for (int r = 0; r < 4; ++r)
      opart[ob + (size_t)(dt * 16 + 4 * g + r) * T + tq] =
          (_Float16)(oa[dt][r] * invL);
  if (g == 0) {
    const size_t pb = (size_t)(chunk * BH + bh) * T + tq;
    mpart[pb] = m;
    lpart[pb] = l;
  }
}

// Combine chunk partials + remove component along normalized v (fp16 cast
// points). 4-way d-split: lane = (q&15) | dgrp<<4, each thread handles 8 of
// 32 d-values; norm^2 and o.vhat dots wave-reduced via shfl_xor(16/32).
__global__ __launch_bounds__(256)
void attn_combine(const _Float16* __restrict__ opart, const float* __restrict__ mpart,
                  const float* __restrict__ lpart, const _Float16* __restrict__ qkv,
                  _Float16* __restrict__ AOh)
{
  const int lane = threadIdx.x & 63;
  const int wv_  = threadIdx.x >> 6;   // wave in block: 0..3
  const int ql   = lane & 15;
  const int dgrp = lane >> 4;          // 0..3
  const int d0   = dgrp * 8;
  const int q  = blockIdx.x * 64 + wv_ * 16 + ql;
  const int bh = blockIdx.y;
  const int b  = bh >> 3, h = bh & 7;

  float mv[NCHUNK], lv[NCHUNK];
  float M = -1e30f;
#pragma unroll
  for (int c = 0; c < NCHUNK; ++c) {
    const size_t pb = (size_t)(c * BH + bh) * T + q;
    mv[c] = mpart[pb];
    lv[c] = lpart[pb];
    M = fmaxf(M, mv[c]);
  }
  float L = 0.f;
  float wc[NCHUNK];
#pragma unroll
  for (int c = 0; c < NCHUNK; ++c) {
    wc[c] = __builtin_amdgcn_exp2f(mv[c] - M) * lv[c];
    L += wc[c];
  }
  const float inv = 1.f / L;
#pragma unroll
  for (int c = 0; c < NCHUNK; ++c) wc[c] *= inv;

  float o[8];
#pragma unroll
  for (int j = 0; j < 8; ++j) o[j] = 0.f;
#pragma unroll
  for (int c = 0; c < NCHUNK; ++c) {
    const size_t ob = (size_t)(c * BH + bh) * HD * T + q;
#pragma unroll
    for (int j = 0; j < 8; ++j)
      o[j] = fmaf(wc[c], (float)opart[ob + (size_t)(d0 + j) * T], o[j]);
  }

  const size_t vbase = ((size_t)b * 3 * C + 2 * C + h * HD) * T + q;
  float vv[8], n2 = 0.f;
#pragma unroll
  for (int j = 0; j < 8; ++j) {
    vv[j] = (float)qkv[vbase + (size_t)(d0 + j) * T];
    n2 = fmaf(vv[j], vv[j], n2);
  }
  n2 += __shfl_xor(n2, 16);
  n2 += __shfl_xor(n2, 32);
  const float nrm = fmaxf(sqrtf(n2), 1e-12f);
  float dot = 0.f;
  float o16[8], vn[8];
#pragma unroll
  for (int j = 0; j < 8; ++j) {
    o16[j] = (float)(_Float16)(o[j]);
    vn[j]  = (float)(_Float16)(vv[j] / nrm);
    dot = fmaf(o16[j], vn[j], dot);
  }
  dot += __shfl_xor(dot, 16);
  dot += __shfl_xor(dot, 32);
  const size_t ab = ((size_t)b * C + h * HD) * T + q;
#pragma unroll
  for (int j = 0; j < 8; ++j)
    AOh[ab + (size_t)(d0 + j) * T] = (_Float16)(o16[j] - dot * vn[j]);
}

__global__ __launch_bounds__(256)
void gn_norm(const float* __restrict__ Y, const float* __restrict__ stats,
             const float* __restrict__ gamma, const float* __restrict__ beta,
             float* __restrict__ O)
{
  const int i = blockIdx.x * 256 + threadIdx.x;
  const int b = i / (C * T);
  const int c = (i / T) & (C - 1);
  const float mu  = stats[b * 2] * INV_N;
  const float var = stats[b * 2 + 1] * INV_N - mu * mu;
  const float r = rsqrtf(var + 1e-5f);
  O[i] = (Y[i] - mu) * r * gamma[c] + beta[c];
}

extern "C" void kernel_launch(void* const* d_in, const int* in_sizes, int n_in,
                              void* d_out, int out_size, void* d_ws, size_t ws_size,
                              hipStream_t stream)
{
  const float* x      = (const float*)d_in[0];
  const float* wq     = (const float*)d_in[1];
  const float* bq     = (const float*)d_in[2];
  const float* wk     = (const float*)d_in[3];
  const float* bk     = (const float*)d_in[4];
  const float* wv     = (const float*)d_in[5];
  const float* bv     = (const float*)d_in[6];
  const float* wo     = (const float*)d_in[7];
  const float* bo     = (const float*)d_in[8];
  const float* gamma1 = (const float*)d_in[9];
  const float* beta1  = (const float*)d_in[10];
  const float* w1     = (const float*)d_in[11];
  const float* bf1    = (const float*)d_in[12];
  const float* w2     = (const float*)d_in[13];
  const float* bf2    = (const float*)d_in[14];
  const float* gamma2 = (const float*)d_in[15];
  const float* beta2  = (const float*)d_in[16];

  char* ws = (char*)d_ws;
  _Float16* qkv16 = (_Float16*)(ws + OFF_QKV);
  _Float16* ao16  = (_Float16*)(ws + OFF_AO);
  _Float16* x1    = (_Float16*)(ws + OFF_X1);
  _Float16* opart = (_Float16*)(ws + OFF_OP);
  float*    mpart = (float*)(ws + OFF_MP);
  float*    lpart = (float*)(ws + OFF_LP);
  _Float16* h16   = (_Float16*)(ws + OFF_H16);
  _Float16* w16   = (_Float16*)(ws + OFF_W16);
  float*    bqkv  = (float*)(ws + OFF_BQKV);
  float*    stats = (float*)(ws + OFF_STATS);
  float*    out   = (float*)d_out;

  const _Float16* wqkv16 = w16;
  const _Float16* wo16   = w16 + N_WQKV;
  const _Float16* w116   = w16 + N_WQKV + N_WO;
  const _Float16* w216   = w16 + N_WQKV + N_WO + N_W1;

  const dim3 blk256(256);

  convert_weights<<<768, blk256, 0, stream>>>(wq, wk, wv, wo, w1, w2, bq, bk, bv,
                                              w16, bqkv, stats);

  // Fused QKV projection: CO=768, K=256, fp32 x in, f16 out
  gemm_mfma<false, false, false, false, false, float, float, _Float16>
      <<<dim3(36, 12, 2), blk256, 0, stream>>>(
          wqkv16, x, bqkv, (const float*)nullptr, qkv16, 3 * C, C,
          nullptr, nullptr, nullptr, nullptr);

  // Flash attention partials (4-way key split, 8-wave blocks) + combine
  attn_mfma<<<dim3(T / 128, NCHUNK, BH), dim3(512), 0, stream>>>(qkv16, opart, mpart, lpart);
  attn_combine<<<dim3(T / 64, BH), blk256, 0, stream>>>(opart, mpart, lpart, qkv16, ao16);

  // Output projection + residual(x, fp32) -> x1 f16 raw; fused GN1 stats
  gemm_mfma<false, true, false, false, true, _Float16, float, _Float16>
      <<<dim3(36, 4, 2), blk256, 0, stream>>>(
          wo16, ao16, bo, x, x1, C, C, nullptr, nullptr, nullptr, stats);

  // FFN1: GN1 applied to staged f16 input, ReLU, f16 out
  gemm_mfma<true, false, true, false, false, _Float16, float, _Float16>
      <<<dim3(36, 16, 2), blk256, 0, stream>>>(
          w116, x1, bf1, (const float*)nullptr, h16, F, C,
          stats, gamma1, beta1, nullptr);

  // FFN2: + GN1(x1 f16) residual -> d_out raw; fused GN2 stats
  gemm_mfma<false, true, false, true, true, _Float16, _Float16, float>
      <<<dim3(36, 4, 2), blk256, 0, stream>>>(
          w216, h16, bf2, x1, out, C, F, stats, gamma1, beta1, stats + 4);

  // GN2 normalize in place on d_out
  gn_norm<<<dim3(4608), blk256, 0, stream>>>(out, stats + 4, gamma2, beta2, out);
}

// Round 19
// 121.970 us; speedup vs baseline: 1.0093x; 1.0093x over previous
//
#include <hip/hip_runtime.h>
#include <hip/hip_fp16.h>

typedef _Float16 f16x8 __attribute__((ext_vector_type(8)));
typedef __fp16 fp16x2 __attribute__((ext_vector_type(2)));   // cvt_pkrtz return type
typedef float f32x4 __attribute__((ext_vector_type(4)));

namespace {

constexpr int B = 2, C = 256, T = 2304, F = 1024, NH = 8, HD = 32;
constexpr int BH = B * NH;           // 16
constexpr int NCHUNK = 4;
constexpr int CHUNK = T / NCHUNK;    // 576
constexpr float C2 = 0.17677669529663687f * 1.4426950408889634f;  // scale*log2(e)
constexpr float INV_N = 1.0f / (float)(C * T);

// f16 weight block sizes (flat elements)
constexpr size_t N_WQKV = (size_t)3 * C * C;   // 196608
constexpr size_t N_WO   = (size_t)C * C;       // 65536
constexpr size_t N_W1   = (size_t)F * C;       // 262144
constexpr size_t N_W2   = (size_t)C * F;       // 262144
constexpr size_t N_WALL = N_WQKV + N_WO + N_W1 + N_W2;

// workspace layout (bytes)
constexpr size_t OFF_QKV  = 0;                                // f16 [B][3C][T]
constexpr size_t SZ_QKV   = (size_t)B * 3 * C * T * 2;
constexpr size_t OFF_AO   = OFF_QKV + SZ_QKV;                 // f16 [B][C][T]
constexpr size_t SZ_AO    = (size_t)B * C * T * 2;
constexpr size_t OFF_X1   = OFF_AO + SZ_AO;                   // f32 [B][C][T] (raw, pre-GN1)
constexpr size_t SZ_X1    = (size_t)B * C * T * 4;
// union region: attention partials, later reused as FFN hidden h16
constexpr size_t OFF_PART = OFF_X1 + SZ_X1;
constexpr size_t SZ_OP    = (size_t)NCHUNK * BH * HD * T * 2; // f16 chunk-normalized O
constexpr size_t SZ_MP    = (size_t)NCHUNK * BH * T * 4;      // f32
constexpr size_t OFF_OP   = OFF_PART;
constexpr size_t OFF_MP   = OFF_OP + SZ_OP;
constexpr size_t OFF_LP   = OFF_MP + SZ_MP;
constexpr size_t SZ_H16   = (size_t)B * F * T * 2;
constexpr size_t SZ_PART  = SZ_OP + 2 * SZ_MP;
constexpr size_t SZ_UNION = SZ_PART > SZ_H16 ? SZ_PART : SZ_H16;
constexpr size_t OFF_H16  = OFF_PART;
constexpr size_t OFF_W16  = OFF_PART + SZ_UNION;              // f16 weights (qkv|wo|w1|w2)
constexpr size_t OFF_BQKV = OFF_W16 + N_WALL * 2;             // f32 [768]
constexpr size_t OFF_STATS = OFF_BQKV + (size_t)3 * C * 4;    // f32 [8]

} // namespace

// Convert all weights fp32 -> f16 into one flat buffer (float4 vectorized);
// concat qkv bias; zero stats.
__global__ __launch_bounds__(256)
void convert_weights(const float* __restrict__ wq, const float* __restrict__ wk,
                     const float* __restrict__ wv, const float* __restrict__ wo,
                     const float* __restrict__ w1, const float* __restrict__ w2,
                     const float* __restrict__ bq, const float* __restrict__ bk,
                     const float* __restrict__ bv,
                     _Float16* __restrict__ w16, float* __restrict__ bqkv,
                     float* __restrict__ stats)
{
  const size_t tid = (size_t)blockIdx.x * 256 + threadIdx.x;
  if (tid < 8) stats[tid] = 0.f;
  if (tid < 3 * C)
    bqkv[tid] = tid < C ? bq[tid] : (tid < 2 * C ? bk[tid - C] : bv[tid - 2 * C]);
  for (size_t i4 = tid; i4 < N_WALL / 4; i4 += (size_t)gridDim.x * 256) {
    const size_t e = i4 * 4;
    const float* src;
    if      (e < 65536)  src = wq + e;
    else if (e < 131072) src = wk + (e - 65536);
    else if (e < 196608) src = wv + (e - 131072);
    else if (e < 262144) src = wo + (e - 196608);
    else if (e < 524288) src = w1 + (e - 262144);
    else                 src = w2 + (e - 524288);
    const float4 v = *(const float4*)src;
    union { _Float16 h[4]; uint2 u; } pk;
    pk.h[0] = (_Float16)v.x; pk.h[1] = (_Float16)v.y;
    pk.h[2] = (_Float16)v.z; pk.h[3] = (_Float16)v.w;
    *(uint2*)(w16 + e) = pk.u;
  }
}

// out[b][co][t] = act( W[co][:] . X[b][:][t] + bias[co] (+ res') )
// 64x64 tile, 4 waves, each wave a 32x32 sub-tile via 2x2 mfma 16x16x32.
// Register prefetch of BOTH X and A-fragments + double-buffered LDS +
// ONE barrier per 32-K step. Packed f32->f16 staging conversion.
template<bool RELU, bool RES, bool GNIN, bool GNRES, bool STATS,
         typename InT, typename OutT>
__global__ __launch_bounds__(256)
void gemm_mfma(const _Float16* __restrict__ W, const InT* __restrict__ X,
               const float* __restrict__ bias, const float* __restrict__ res,
               OutT* __restrict__ out, int CO, int K,
               const float* __restrict__ stats_in,
               const float* __restrict__ gamma, const float* __restrict__ beta,
               float* __restrict__ stats_out)
{
  const int b   = blockIdx.z;
  const int co0 = blockIdx.y * 64;
  const int t0  = blockIdx.x * 64;
  const int tid = threadIdx.x;
  const int wid = tid >> 6, lane = tid & 63;
  const int g = lane >> 4, lo = lane & 15;
  const int wm = wid & 1, wn = wid >> 1;

  __shared__ f16x8 xs[2][4][64];   // double-buffered [k/8][t] 32-k step
  __shared__ float gs[256], bs[256];
  __shared__ float red[8];

  float mu = 0.f, rsig = 0.f;
  if (GNIN || GNRES) {
    const float s1 = stats_in[b * 2], s2 = stats_in[b * 2 + 1];
    mu = s1 * INV_N;
    rsig = rsqrtf(s2 * INV_N - mu * mu + 1e-5f);
  }
  if (GNIN) { gs[tid] = gamma[tid]; bs[tid] = beta[tid]; }

  const f32x4 z4 = {0.f, 0.f, 0.f, 0.f};
  f32x4 acc00 = z4, acc01 = z4, acc10 = z4, acc11 = z4;

  const int st = tid & 63;   // staged t within tile
  const int kp = tid >> 6;   // staged k/8 within step
  const InT* Xp = X + (size_t)b * K * T + t0 + st;
  const _Float16* Wp = W + (size_t)(co0 + wm * 32 + lo) * K + 8 * g;

  // prologue: step-0 X floats and A-frags into regs
  float xr[8];
#pragma unroll
  for (int j = 0; j < 8; ++j) xr[j] = (float)Xp[(size_t)(kp * 8 + j) * T];
  f16x8 afc0 = *(const f16x8*)(Wp);
  f16x8 afc1 = *(const f16x8*)(Wp + (size_t)16 * K);

  __syncthreads();   // gs/bs visible before first staged write uses them

  int it = 0;
  for (int k0 = 0; k0 < K; k0 += 32, ++it) {
    const int buf = it & 1;
    // write current staged regs to LDS[buf] (packed cvt)
    union { fp16x2 h2[4]; f16x8 v8; } u;
#pragma unroll
    for (int j2 = 0; j2 < 4; ++j2) {
      float v0 = xr[2 * j2], v1 = xr[2 * j2 + 1];
      if (GNIN) {
        const int k = k0 + kp * 8 + 2 * j2;
        v0 = (v0 - mu) * rsig * gs[k] + bs[k];
        v1 = (v1 - mu) * rsig * gs[k + 1] + bs[k + 1];
      }
      u.h2[j2] = __builtin_amdgcn_cvt_pkrtz(v0, v1);
    }
    xs[buf][kp][st] = u.v8;

    // issue next step's X and A loads (clamped; redundant on last iter)
    const int k1 = (k0 + 32 < K) ? k0 + 32 : k0;
#pragma unroll
    for (int j = 0; j < 8; ++j) xr[j] = (float)Xp[(size_t)(k1 + kp * 8 + j) * T];
    const f16x8 afn0 = *(const f16x8*)(Wp + (size_t)k1);
    const f16x8 afn1 = *(const f16x8*)(Wp + (size_t)16 * K + k1);

    __syncthreads();   // staging of LDS[buf] complete for all waves

    const f16x8 bf0 = xs[buf][g][wn * 32 + lo];
    const f16x8 bf1 = xs[buf][g][wn * 32 + 16 + lo];
    acc00 = __builtin_amdgcn_mfma_f32_16x16x32_f16(afc0, bf0, acc00, 0, 0, 0);
    acc01 = __builtin_amdgcn_mfma_f32_16x16x32_f16(afc0, bf1, acc01, 0, 0, 0);
    acc10 = __builtin_amdgcn_mfma_f32_16x16x32_f16(afc1, bf0, acc10, 0, 0, 0);
    acc11 = __builtin_amdgcn_mfma_f32_16x16x32_f16(afc1, bf1, acc11, 0, 0, 0);

    afc0 = afn0;
    afc1 = afn1;
  }

  float s = 0.f, ss = 0.f;
  const size_t obase = ((size_t)b * CO + co0 + wm * 32) * T + t0 + wn * 32 + lo;
  const float* resb = res + obase;   // valid only if RES
  OutT* outb = out + obase;
  const f32x4 accs[2][2] = {{acc00, acc01}, {acc10, acc11}};
#pragma unroll
  for (int mi = 0; mi < 2; ++mi) {
#pragma unroll
    for (int r = 0; r < 4; ++r) {
      const int row = mi * 16 + 4 * g + r;
      const int co = co0 + wm * 32 + row;
      const float bi = bias[co];
      float gm = 0.f, bt = 0.f;
      if (GNRES) { gm = gamma[co]; bt = beta[co]; }
#pragma unroll
      for (int ni = 0; ni < 2; ++ni) {
        float v = accs[mi][ni][r] + bi;
        if (RES) {
          float rv = resb[(size_t)row * T + ni * 16];
          if (GNRES) rv = (rv - mu) * rsig * gm + bt;
          v += rv;
        }
        if (RELU) v = fmaxf(v, 0.f);
        outb[(size_t)row * T + ni * 16] = (OutT)v;
        if (STATS) { s += v; ss = fmaf(v, v, ss); }
      }
    }
  }

  if (STATS) {
#pragma unroll
    for (int off = 32; off > 0; off >>= 1) {
      s  += __shfl_down(s, off);
      ss += __shfl_down(ss, off);
    }
    if (lane == 0) { red[wid] = s; red[4 + wid] = ss; }
    __syncthreads();
    if (tid == 0) {
      atomicAdd(&stats_out[b * 2],     red[0] + red[1] + red[2] + red[3]);
      atomicAdd(&stats_out[b * 2 + 1], red[4] + red[5] + red[6] + red[7]);
    }
  }
}

// Flash-attention partials over one key chunk (MFMA, exp2-domain softmax).
// 8 waves / 128 queries per block; double-buffered K/V LDS staging, single
// barrier per iter; defer-max (skip rescale when max unchanged, bit-exact);
// packed P conversion; K-stage uses single ds_write_b64. Q pre-scaled.
__global__ __launch_bounds__(512)
void attn_mfma(const _Float16* __restrict__ qkv, _Float16* __restrict__ opart,
               float* __restrict__ mpart, float* __restrict__ lpart)
{
  const int tid  = threadIdx.x;
  const int wid  = tid >> 6;       // 0..7
  const int lane = tid & 63;
  const int g    = lane >> 4;
  const int lo   = lane & 15;
  const int chunk = blockIdx.y;
  const int bh   = blockIdx.z;
  const int b    = bh >> 3, h = bh & 7;
  const int tq   = blockIdx.x * 128 + wid * 16 + lo;
  const size_t qb = ((size_t)b * 3 * C + h * HD) * T;
  const size_t kb = qb + (size_t)C * T;
  const size_t vb = qb + (size_t)2 * C * T;

  __shared__ _Float16 kt[2][64][36];   // [buf][tk][d] transposed K tile
  __shared__ _Float16 vt[2][32][72];   // [buf][d][tk] V tile
  __shared__ _Float16 pl[8][16][72];   // per-wave P: [tq][tk]

  // staging thread roles (512 threads)
  const int t   = tid & 63;    // K stage: key index
  const int dp  = tid >> 6;    // K stage: d-quad group (0..7)
  const int dv  = tid >> 4;    // V stage: d (0..31)
  const int seg = tid & 15;    // V stage: 4-key segment

  // Q fragment pre-scaled by C2 (f32 multiply, then f16)
  f16x8 qf;
#pragma unroll
  for (int j = 0; j < 8; ++j)
    qf[j] = (_Float16)((float)qkv[qb + (size_t)(8 * g + j) * T + tq] * C2);

  const f32x4 zero4 = {0.f, 0.f, 0.f, 0.f};
  f32x4 oa[2] = {zero4, zero4};
  float m = -1e30f, l = 0.f;

  constexpr int NIT = CHUNK / 64;

  // prologue: load tile 0 into regs
  ushort ka[4];
  uint2  va;
  {
    const int tk0 = chunk * CHUNK;
#pragma unroll
    for (int dd = 0; dd < 4; ++dd)
      ka[dd] = *(const ushort*)(qkv + kb + (size_t)(dp * 4 + dd) * T + tk0 + t);
    va = *(const uint2*)(qkv + vb + (size_t)dv * T + tk0 + seg * 4);
  }

  for (int it = 0; it < NIT; ++it) {
    const int buf = it & 1;

    // write current staged regs to LDS[buf] (single b64 for K)
    {
      uint2 kw;
      kw.x = (uint)ka[0] | ((uint)ka[1] << 16);
      kw.y = (uint)ka[2] | ((uint)ka[3] << 16);
      *(uint2*)&kt[buf][t][dp * 4] = kw;
    }
    *(uint2*)&vt[buf][dv][seg * 4] = va;

    // issue next tile's global loads (clamped; redundant on last iter)
    {
      const int tkn = chunk * CHUNK + (it + 1 < NIT ? it + 1 : it) * 64;
      ushort ka2[4];
      uint2  va2;
#pragma unroll
      for (int dd = 0; dd < 4; ++dd)
        ka2[dd] = *(const ushort*)(qkv + kb + (size_t)(dp * 4 + dd) * T + tkn + t);
      va2 = *(const uint2*)(qkv + vb + (size_t)dv * T + tkn + seg * 4);

      __syncthreads();   // staging of LDS[buf] complete for all waves

      // ---- compute on LDS[buf] ----
      f32x4 s4[4];
#pragma unroll
      for (int mt = 0; mt < 4; ++mt) {
        union { f16x8 v; uint2 u[2]; } kf;
        const _Float16* kr = &kt[buf][mt * 16 + lo][8 * g];
        kf.u[0] = *(const uint2*)(kr);
        kf.u[1] = *(const uint2*)(kr + 4);
        s4[mt] = __builtin_amdgcn_mfma_f32_16x16x32_f16(kf.v, qf, zero4, 0, 0, 0);
      }
      // lane holds S^T[tk = mt*16 + 4g + r][tq = lo]; already base-2 domain
      float rmax = -1e30f;
#pragma unroll
      for (int mt = 0; mt < 4; ++mt) {
        const float m01 = fmaxf(s4[mt][0], s4[mt][1]);
        const float m23 = fmaxf(s4[mt][2], s4[mt][3]);
        rmax = fmaxf(rmax, fmaxf(m01, m23));
      }
      rmax = fmaxf(rmax, __shfl_xor(rmax, 16));
      rmax = fmaxf(rmax, __shfl_xor(rmax, 32));
      // defer-max: when rmax <= m, fsc == 1 exactly -> skip rescale (bit-exact)
      if (!__all(rmax <= m)) {
        const float mn = fmaxf(m, rmax);
        const float fsc = __builtin_amdgcn_exp2f(m - mn);
        m = mn;
        l *= fsc;
#pragma unroll
        for (int dt = 0; dt < 2; ++dt)
#pragma unroll
          for (int r = 0; r < 4; ++r) oa[dt][r] *= fsc;
      }
      float p[4][4];
      float psum = 0.f;
#pragma unroll
      for (int mt = 0; mt < 4; ++mt)
#pragma unroll
        for (int r = 0; r < 4; ++r) {
          p[mt][r] = __builtin_amdgcn_exp2f(s4[mt][r] - m);
          psum += p[mt][r];
        }
      psum += __shfl_xor(psum, 16);
      psum += __shfl_xor(psum, 32);
      l += psum;

      // P -> per-wave LDS (packed cvt, b64 writes), then read B-frags (b128)
#pragma unroll
      for (int mt = 0; mt < 4; ++mt) {
        union { fp16x2 h2[2]; uint2 u2; } pw;
        pw.h2[0] = __builtin_amdgcn_cvt_pkrtz(p[mt][0], p[mt][1]);
        pw.h2[1] = __builtin_amdgcn_cvt_pkrtz(p[mt][2], p[mt][3]);
        *(uint2*)&pl[wid][lo][16 * mt + 4 * g] = pw.u2;
      }
#pragma unroll
      for (int c2 = 0; c2 < 2; ++c2) {
        const f16x8 pbv = *(const f16x8*)&pl[wid][lo][c2 * 32 + 8 * g];
#pragma unroll
        for (int dt = 0; dt < 2; ++dt) {
          const f16x8 vf = *(const f16x8*)&vt[buf][dt * 16 + lo][c2 * 32 + 8 * g];
          oa[dt] = __builtin_amdgcn_mfma_f32_16x16x32_f16(vf, pbv, oa[dt], 0, 0, 0);
        }
      }

      // carry prefetched regs into next iter
#pragma unroll
      for (int dd = 0; dd < 4; ++dd) ka[dd] = ka2[dd];
      va = va2;
    }
  }

  // epilogue: store chunk-normalized O (f16) + m,l
  const float invL = 1.f / l;
  const size_t ob = (size_t)(chunk * BH + bh) * HD * T;
#pragma unroll
  for (int dt = 0; dt < 2; ++dt)
#pragma unroll
    for (int r = 0; r < 4; ++r)
      opart[ob + (size_t)(dt * 16 + 4 * g + r) * T + tq] =
          (_Float16)(oa[dt][r] * invL);
  if (g == 0) {
    const size_t pb = (size_t)(chunk * BH + bh) * T + tq;
    mpart[pb] = m;
    lpart[pb] = l;
  }
}

// Combine chunk partials + remove component along normalized v (fp16 cast
// points). 4-way d-split: lane = (q&15) | dgrp<<4, each thread handles 8 of
// 32 d-values; norm^2 and o.vhat dots wave-reduced via shfl_xor(16/32).
__global__ __launch_bounds__(256)
void attn_combine(const _Float16* __restrict__ opart, const float* __restrict__ mpart,
                  const float* __restrict__ lpart, const _Float16* __restrict__ qkv,
                  _Float16* __restrict__ AOh)
{
  const int lane = threadIdx.x & 63;
  const int wv_  = threadIdx.x >> 6;   // wave in block: 0..3
  const int ql   = lane & 15;
  const int dgrp = lane >> 4;          // 0..3
  const int d0   = dgrp * 8;
  const int q  = blockIdx.x * 64 + wv_ * 16 + ql;
  const int bh = blockIdx.y;
  const int b  = bh >> 3, h = bh & 7;

  float mv[NCHUNK], lv[NCHUNK];
  float M = -1e30f;
#pragma unroll
  for (int c = 0; c < NCHUNK; ++c) {
    const size_t pb = (size_t)(c * BH + bh) * T + q;
    mv[c] = mpart[pb];
    lv[c] = lpart[pb];
    M = fmaxf(M, mv[c]);
  }
  float L = 0.f;
  float wc[NCHUNK];
#pragma unroll
  for (int c = 0; c < NCHUNK; ++c) {
    wc[c] = __builtin_amdgcn_exp2f(mv[c] - M) * lv[c];
    L += wc[c];
  }
  const float inv = 1.f / L;
#pragma unroll
  for (int c = 0; c < NCHUNK; ++c) wc[c] *= inv;

  float o[8];
#pragma unroll
  for (int j = 0; j < 8; ++j) o[j] = 0.f;
#pragma unroll
  for (int c = 0; c < NCHUNK; ++c) {
    const size_t ob = (size_t)(c * BH + bh) * HD * T + q;
#pragma unroll
    for (int j = 0; j < 8; ++j)
      o[j] = fmaf(wc[c], (float)opart[ob + (size_t)(d0 + j) * T], o[j]);
  }

  const size_t vbase = ((size_t)b * 3 * C + 2 * C + h * HD) * T + q;
  float vv[8], n2 = 0.f;
#pragma unroll
  for (int j = 0; j < 8; ++j) {
    vv[j] = (float)qkv[vbase + (size_t)(d0 + j) * T];
    n2 = fmaf(vv[j], vv[j], n2);
  }
  n2 += __shfl_xor(n2, 16);
  n2 += __shfl_xor(n2, 32);
  const float nrm = fmaxf(sqrtf(n2), 1e-12f);
  float dot = 0.f;
  float o16[8], vn[8];
#pragma unroll
  for (int j = 0; j < 8; ++j) {
    o16[j] = (float)(_Float16)(o[j]);
    vn[j]  = (float)(_Float16)(vv[j] / nrm);
    dot = fmaf(o16[j], vn[j], dot);
  }
  dot += __shfl_xor(dot, 16);
  dot += __shfl_xor(dot, 32);
  const size_t ab = ((size_t)b * C + h * HD) * T + q;
#pragma unroll
  for (int j = 0; j < 8; ++j)
    AOh[ab + (size_t)(d0 + j) * T] = (_Float16)(o16[j] - dot * vn[j]);
}

__global__ __launch_bounds__(256)
void gn_norm(const float* __restrict__ Y, const float* __restrict__ stats,
             const float* __restrict__ gamma, const float* __restrict__ beta,
             float* __restrict__ O)
{
  const int i = blockIdx.x * 256 + threadIdx.x;
  const int b = i / (C * T);
  const int c = (i / T) & (C - 1);
  const float mu  = stats[b * 2] * INV_N;
  const float var = stats[b * 2 + 1] * INV_N - mu * mu;
  const float r = rsqrtf(var + 1e-5f);
  O[i] = (Y[i] - mu) * r * gamma[c] + beta[c];
}

extern "C" void kernel_launch(void* const* d_in, const int* in_sizes, int n_in,
                              void* d_out, int out_size, void* d_ws, size_t ws_size,
                              hipStream_t stream)
{
  const float* x      = (const float*)d_in[0];
  const float* wq     = (const float*)d_in[1];
  const float* bq     = (const float*)d_in[2];
  const float* wk     = (const float*)d_in[3];
  const float* bk     = (const float*)d_in[4];
  const float* wv     = (const float*)d_in[5];
  const float* bv     = (const float*)d_in[6];
  const float* wo     = (const float*)d_in[7];
  const float* bo     = (const float*)d_in[8];
  const float* gamma1 = (const float*)d_in[9];
  const float* beta1  = (const float*)d_in[10];
  const float* w1     = (const float*)d_in[11];
  const float* bf1    = (const float*)d_in[12];
  const float* w2     = (const float*)d_in[13];
  const float* bf2    = (const float*)d_in[14];
  const float* gamma2 = (const float*)d_in[15];
  const float* beta2  = (const float*)d_in[16];

  char* ws = (char*)d_ws;
  _Float16* qkv16 = (_Float16*)(ws + OFF_QKV);
  _Float16* ao16  = (_Float16*)(ws + OFF_AO);
  float*    x1    = (float*)(ws + OFF_X1);
  _Float16* opart = (_Float16*)(ws + OFF_OP);
  float*    mpart = (float*)(ws + OFF_MP);
  float*    lpart = (float*)(ws + OFF_LP);
  _Float16* h16   = (_Float16*)(ws + OFF_H16);
  _Float16* w16   = (_Float16*)(ws + OFF_W16);
  float*    bqkv  = (float*)(ws + OFF_BQKV);
  float*    stats = (float*)(ws + OFF_STATS);
  float*    out   = (float*)d_out;

  const _Float16* wqkv16 = w16;
  const _Float16* wo16   = w16 + N_WQKV;
  const _Float16* w116   = w16 + N_WQKV + N_WO;
  const _Float16* w216   = w16 + N_WQKV + N_WO + N_W1;

  const dim3 blk256(256);

  convert_weights<<<768, blk256, 0, stream>>>(wq, wk, wv, wo, w1, w2, bq, bk, bv,
                                              w16, bqkv, stats);

  // Fused QKV projection: CO=768, K=256, fp32 x in, f16 out
  gemm_mfma<false, false, false, false, false, float, _Float16>
      <<<dim3(36, 12, 2), blk256, 0, stream>>>(
          wqkv16, x, bqkv, nullptr, qkv16, 3 * C, C, nullptr, nullptr, nullptr, nullptr);

  // Flash attention partials (4-way key split, 8-wave blocks) + combine
  attn_mfma<<<dim3(T / 128, NCHUNK, BH), dim3(512), 0, stream>>>(qkv16, opart, mpart, lpart);
  attn_combine<<<dim3(T / 64, BH), blk256, 0, stream>>>(opart, mpart, lpart, qkv16, ao16);

  // Output projection + residual -> x1 raw; fused GN1 stats
  gemm_mfma<false, true, false, false, true, _Float16, float>
      <<<dim3(36, 4, 2), blk256, 0, stream>>>(
          wo16, ao16, bo, x, x1, C, C, nullptr, nullptr, nullptr, stats);

  // FFN1: GN1 applied to staged input, ReLU, f16 out
  gemm_mfma<true, false, true, false, false, float, _Float16>
      <<<dim3(36, 16, 2), blk256, 0, stream>>>(
          w116, x1, bf1, nullptr, h16, F, C, stats, gamma1, beta1, nullptr);

  // FFN2: + GN1(x1raw) residual -> d_out raw; fused GN2 stats
  gemm_mfma<false, true, false, true, true, _Float16, float>
      <<<dim3(36, 4, 2), blk256, 0, stream>>>(
          w216, h16, bf2, x1, out, C, F, stats, gamma1, beta1, stats + 4);

  // GN2 normalize in place on d_out
  gn_norm<<<dim3(4608), blk256, 0, stream>>>(out, stats + 4, gamma2, beta2, out);
}

// Round 20
// 121.173 us; speedup vs baseline: 1.0159x; 1.0066x over previous
//
#include <hip/hip_runtime.h>
#include <hip/hip_fp16.h>

typedef _Float16 f16x8 __attribute__((ext_vector_type(8)));
typedef __fp16 fp16x2 __attribute__((ext_vector_type(2)));   // cvt_pkrtz return type
typedef float f32x4 __attribute__((ext_vector_type(4)));

namespace {

constexpr int B = 2, C = 256, T = 2304, F = 1024, NH = 8, HD = 32;
constexpr int BH = B * NH;           // 16
constexpr int NCHUNK = 4;
constexpr int CHUNK = T / NCHUNK;    // 576
constexpr float C2 = 0.17677669529663687f * 1.4426950408889634f;  // scale*log2(e)
constexpr float INV_N = 1.0f / (float)(C * T);

// f16 weight block sizes (flat elements)
constexpr size_t N_WQKV = (size_t)3 * C * C;   // 196608
constexpr size_t N_WO   = (size_t)C * C;       // 65536
constexpr size_t N_W1   = (size_t)F * C;       // 262144
constexpr size_t N_W2   = (size_t)C * F;       // 262144
constexpr size_t N_WALL = N_WQKV + N_WO + N_W1 + N_W2;

// workspace layout (bytes)
constexpr size_t OFF_QKV  = 0;                                // f16 [B][3C][T]
constexpr size_t SZ_QKV   = (size_t)B * 3 * C * T * 2;
constexpr size_t OFF_AO   = OFF_QKV + SZ_QKV;                 // f16 [B][C][T]
constexpr size_t SZ_AO    = (size_t)B * C * T * 2;
constexpr size_t OFF_X1   = OFF_AO + SZ_AO;                   // f32 [B][C][T] (raw, pre-GN1)
constexpr size_t SZ_X1    = (size_t)B * C * T * 4;
// union region: attention partials, later reused as FFN hidden h16
constexpr size_t OFF_PART = OFF_X1 + SZ_X1;
constexpr size_t SZ_OP    = (size_t)NCHUNK * BH * HD * T * 2; // f16 chunk-normalized O
constexpr size_t SZ_MP    = (size_t)NCHUNK * BH * T * 4;      // f32
constexpr size_t OFF_OP   = OFF_PART;
constexpr size_t OFF_MP   = OFF_OP + SZ_OP;
constexpr size_t OFF_LP   = OFF_MP + SZ_MP;
constexpr size_t SZ_H16   = (size_t)B * F * T * 2;
constexpr size_t SZ_PART  = SZ_OP + 2 * SZ_MP;
constexpr size_t SZ_UNION = SZ_PART > SZ_H16 ? SZ_PART : SZ_H16;
constexpr size_t OFF_H16  = OFF_PART;
constexpr size_t OFF_W16  = OFF_PART + SZ_UNION;              // f16 weights (qkv|wo|w1|w2)
constexpr size_t OFF_BQKV = OFF_W16 + N_WALL * 2;             // f32 [768]
constexpr size_t OFF_STATS = OFF_BQKV + (size_t)3 * C * 4;    // f32 [8]

} // namespace

// Convert all weights fp32 -> f16 into one flat buffer (float4 vectorized);
// concat qkv bias; zero stats.
__global__ __launch_bounds__(256)
void convert_weights(const float* __restrict__ wq, const float* __restrict__ wk,
                     const float* __restrict__ wv, const float* __restrict__ wo,
                     const float* __restrict__ w1, const float* __restrict__ w2,
                     const float* __restrict__ bq, const float* __restrict__ bk,
                     const float* __restrict__ bv,
                     _Float16* __restrict__ w16, float* __restrict__ bqkv,
                     float* __restrict__ stats)
{
  const size_t tid = (size_t)blockIdx.x * 256 + threadIdx.x;
  if (tid < 8) stats[tid] = 0.f;
  if (tid < 3 * C)
    bqkv[tid] = tid < C ? bq[tid] : (tid < 2 * C ? bk[tid - C] : bv[tid - 2 * C]);
  for (size_t i4 = tid; i4 < N_WALL / 4; i4 += (size_t)gridDim.x * 256) {
    const size_t e = i4 * 4;
    const float* src;
    if      (e < 65536)  src = wq + e;
    else if (e < 131072) src = wk + (e - 65536);
    else if (e < 196608) src = wv + (e - 131072);
    else if (e < 262144) src = wo + (e - 196608);
    else if (e < 524288) src = w1 + (e - 262144);
    else                 src = w2 + (e - 524288);
    const float4 v = *(const float4*)src;
    union { _Float16 h[4]; uint2 u; } pk;
    pk.h[0] = (_Float16)v.x; pk.h[1] = (_Float16)v.y;
    pk.h[2] = (_Float16)v.z; pk.h[3] = (_Float16)v.w;
    *(uint2*)(w16 + e) = pk.u;
  }
}

// out[b][co][t] = act( W[co][:] . X[b][:][t] + bias[co] (+ res') )
// 64x64 tile, 4 waves, each wave a 32x32 sub-tile via 2x2 mfma 16x16x32.
// Register prefetch of BOTH X and A-fragments + double-buffered LDS +
// ONE barrier per 32-K step. Packed f32->f16 staging conversion.
template<bool RELU, bool RES, bool GNIN, bool GNRES, bool STATS,
         typename InT, typename OutT>
__global__ __launch_bounds__(256)
void gemm_mfma(const _Float16* __restrict__ W, const InT* __restrict__ X,
               const float* __restrict__ bias, const float* __restrict__ res,
               OutT* __restrict__ out, int CO, int K,
               const float* __restrict__ stats_in,
               const float* __restrict__ gamma, const float* __restrict__ beta,
               float* __restrict__ stats_out)
{
  const int b   = blockIdx.z;
  const int co0 = blockIdx.y * 64;
  const int t0  = blockIdx.x * 64;
  const int tid = threadIdx.x;
  const int wid = tid >> 6, lane = tid & 63;
  const int g = lane >> 4, lo = lane & 15;
  const int wm = wid & 1, wn = wid >> 1;

  __shared__ f16x8 xs[2][4][64];   // double-buffered [k/8][t] 32-k step
  __shared__ float gs[256], bs[256];
  __shared__ float red[8];

  float mu = 0.f, rsig = 0.f;
  if (GNIN || GNRES) {
    const float s1 = stats_in[b * 2], s2 = stats_in[b * 2 + 1];
    mu = s1 * INV_N;
    rsig = rsqrtf(s2 * INV_N - mu * mu + 1e-5f);
  }
  if (GNIN) { gs[tid] = gamma[tid]; bs[tid] = beta[tid]; }

  const f32x4 z4 = {0.f, 0.f, 0.f, 0.f};
  f32x4 acc00 = z4, acc01 = z4, acc10 = z4, acc11 = z4;

  const int st = tid & 63;   // staged t within tile
  const int kp = tid >> 6;   // staged k/8 within step
  const InT* Xp = X + (size_t)b * K * T + t0 + st;
  const _Float16* Wp = W + (size_t)(co0 + wm * 32 + lo) * K + 8 * g;

  // prologue: step-0 X floats and A-frags into regs
  float xr[8];
#pragma unroll
  for (int j = 0; j < 8; ++j) xr[j] = (float)Xp[(size_t)(kp * 8 + j) * T];
  f16x8 afc0 = *(const f16x8*)(Wp);
  f16x8 afc1 = *(const f16x8*)(Wp + (size_t)16 * K);

  __syncthreads();   // gs/bs visible before first staged write uses them

  int it = 0;
  for (int k0 = 0; k0 < K; k0 += 32, ++it) {
    const int buf = it & 1;
    // write current staged regs to LDS[buf] (packed cvt)
    union { fp16x2 h2[4]; f16x8 v8; } u;
#pragma unroll
    for (int j2 = 0; j2 < 4; ++j2) {
      float v0 = xr[2 * j2], v1 = xr[2 * j2 + 1];
      if (GNIN) {
        const int k = k0 + kp * 8 + 2 * j2;
        v0 = (v0 - mu) * rsig * gs[k] + bs[k];
        v1 = (v1 - mu) * rsig * gs[k + 1] + bs[k + 1];
      }
      u.h2[j2] = __builtin_amdgcn_cvt_pkrtz(v0, v1);
    }
    xs[buf][kp][st] = u.v8;

    // issue next step's X and A loads (clamped; redundant on last iter)
    const int k1 = (k0 + 32 < K) ? k0 + 32 : k0;
#pragma unroll
    for (int j = 0; j < 8; ++j) xr[j] = (float)Xp[(size_t)(k1 + kp * 8 + j) * T];
    const f16x8 afn0 = *(const f16x8*)(Wp + (size_t)k1);
    const f16x8 afn1 = *(const f16x8*)(Wp + (size_t)16 * K + k1);

    __syncthreads();   // staging of LDS[buf] complete for all waves

    const f16x8 bf0 = xs[buf][g][wn * 32 + lo];
    const f16x8 bf1 = xs[buf][g][wn * 32 + 16 + lo];
    acc00 = __builtin_amdgcn_mfma_f32_16x16x32_f16(afc0, bf0, acc00, 0, 0, 0);
    acc01 = __builtin_amdgcn_mfma_f32_16x16x32_f16(afc0, bf1, acc01, 0, 0, 0);
    acc10 = __builtin_amdgcn_mfma_f32_16x16x32_f16(afc1, bf0, acc10, 0, 0, 0);
    acc11 = __builtin_amdgcn_mfma_f32_16x16x32_f16(afc1, bf1, acc11, 0, 0, 0);

    afc0 = afn0;
    afc1 = afn1;
  }

  float s = 0.f, ss = 0.f;
  const size_t obase = ((size_t)b * CO + co0 + wm * 32) * T + t0 + wn * 32 + lo;
  const float* resb = res + obase;   // valid only if RES
  OutT* outb = out + obase;
  const f32x4 accs[2][2] = {{acc00, acc01}, {acc10, acc11}};
#pragma unroll
  for (int mi = 0; mi < 2; ++mi) {
#pragma unroll
    for (int r = 0; r < 4; ++r) {
      const int row = mi * 16 + 4 * g + r;
      const int co = co0 + wm * 32 + row;
      const float bi = bias[co];
      float gm = 0.f, bt = 0.f;
      if (GNRES) { gm = gamma[co]; bt = beta[co]; }
#pragma unroll
      for (int ni = 0; ni < 2; ++ni) {
        float v = accs[mi][ni][r] + bi;
        if (RES) {
          float rv = resb[(size_t)row * T + ni * 16];
          if (GNRES) rv = (rv - mu) * rsig * gm + bt;
          v += rv;
        }
        if (RELU) v = fmaxf(v, 0.f);
        outb[(size_t)row * T + ni * 16] = (OutT)v;
        if (STATS) { s += v; ss = fmaf(v, v, ss); }
      }
    }
  }

  if (STATS) {
#pragma unroll
    for (int off = 32; off > 0; off >>= 1) {
      s  += __shfl_down(s, off);
      ss += __shfl_down(ss, off);
    }
    if (lane == 0) { red[wid] = s; red[4 + wid] = ss; }
    __syncthreads();
    if (tid == 0) {
      atomicAdd(&stats_out[b * 2],     red[0] + red[1] + red[2] + red[3]);
      atomicAdd(&stats_out[b * 2 + 1], red[4] + red[5] + red[6] + red[7]);
    }
  }
}

// Flash-attention partials over one key chunk (MFMA, exp2-domain softmax).
// 8 waves / 128 queries per block; double-buffered K/V LDS staging, single
// barrier per iter; defer-max (skip rescale when max unchanged, bit-exact);
// packed P conversion. Q pre-scaled by scale*log2(e).
__global__ __launch_bounds__(512)
void attn_mfma(const _Float16* __restrict__ qkv, _Float16* __restrict__ opart,
               float* __restrict__ mpart, float* __restrict__ lpart)
{
  const int tid  = threadIdx.x;
  const int wid  = tid >> 6;       // 0..7
  const int lane = tid & 63;
  const int g    = lane >> 4;
  const int lo   = lane & 15;
  const int chunk = blockIdx.y;
  const int bh   = blockIdx.z;
  const int b    = bh >> 3, h = bh & 7;
  const int tq   = blockIdx.x * 128 + wid * 16 + lo;
  const size_t qb = ((size_t)b * 3 * C + h * HD) * T;
  const size_t kb = qb + (size_t)C * T;
  const size_t vb = qb + (size_t)2 * C * T;

  __shared__ _Float16 kt[2][64][36];   // [buf][tk][d] transposed K tile
  __shared__ _Float16 vt[2][32][72];   // [buf][d][tk] V tile
  __shared__ _Float16 pl[8][16][72];   // per-wave P: [tq][tk]

  // staging thread roles (512 threads)
  const int t   = tid & 63;    // K stage: key index
  const int dp  = tid >> 6;    // K stage: d-quad group (0..7)
  const int dv  = tid >> 4;    // V stage: d (0..31)
  const int seg = tid & 15;    // V stage: 4-key segment

  // Q fragment pre-scaled by C2 (f32 multiply, then f16)
  f16x8 qf;
#pragma unroll
  for (int j = 0; j < 8; ++j)
    qf[j] = (_Float16)((float)qkv[qb + (size_t)(8 * g + j) * T + tq] * C2);

  const f32x4 zero4 = {0.f, 0.f, 0.f, 0.f};
  f32x4 oa[2] = {zero4, zero4};
  float m = -1e30f, l = 0.f;

  constexpr int NIT = CHUNK / 64;

  // prologue: load tile 0 into regs
  ushort ka[4];
  uint2  va;
  {
    const int tk0 = chunk * CHUNK;
#pragma unroll
    for (int dd = 0; dd < 4; ++dd)
      ka[dd] = *(const ushort*)(qkv + kb + (size_t)(dp * 4 + dd) * T + tk0 + t);
    va = *(const uint2*)(qkv + vb + (size_t)dv * T + tk0 + seg * 4);
  }

  for (int it = 0; it < NIT; ++it) {
    const int buf = it & 1;

    // write current staged regs to LDS[buf]
    *(uint*)&kt[buf][t][dp * 4]     = (uint)ka[0] | ((uint)ka[1] << 16);
    *(uint*)&kt[buf][t][dp * 4 + 2] = (uint)ka[2] | ((uint)ka[3] << 16);
    *(uint2*)&vt[buf][dv][seg * 4] = va;

    // issue next tile's global loads (clamped; redundant on last iter)
    {
      const int tkn = chunk * CHUNK + (it + 1 < NIT ? it + 1 : it) * 64;
      ushort ka2[4];
      uint2  va2;
#pragma unroll
      for (int dd = 0; dd < 4; ++dd)
        ka2[dd] = *(const ushort*)(qkv + kb + (size_t)(dp * 4 + dd) * T + tkn + t);
      va2 = *(const uint2*)(qkv + vb + (size_t)dv * T + tkn + seg * 4);

      __syncthreads();   // staging of LDS[buf] complete for all waves

      // ---- compute on LDS[buf] ----
      f32x4 s4[4];
#pragma unroll
      for (int mt = 0; mt < 4; ++mt) {
        union { f16x8 v; uint2 u[2]; } kf;
        const _Float16* kr = &kt[buf][mt * 16 + lo][8 * g];
        kf.u[0] = *(const uint2*)(kr);
        kf.u[1] = *(const uint2*)(kr + 4);
        s4[mt] = __builtin_amdgcn_mfma_f32_16x16x32_f16(kf.v, qf, zero4, 0, 0, 0);
      }
      // lane holds S^T[tk = mt*16 + 4g + r][tq = lo]; already base-2 domain
      float rmax = -1e30f;
#pragma unroll
      for (int mt = 0; mt < 4; ++mt) {
        const float m01 = fmaxf(s4[mt][0], s4[mt][1]);
        const float m23 = fmaxf(s4[mt][2], s4[mt][3]);
        rmax = fmaxf(rmax, fmaxf(m01, m23));
      }
      rmax = fmaxf(rmax, __shfl_xor(rmax, 16));
      rmax = fmaxf(rmax, __shfl_xor(rmax, 32));
      // defer-max: when rmax <= m, fsc == 1 exactly -> skip rescale (bit-exact)
      if (!__all(rmax <= m)) {
        const float mn = fmaxf(m, rmax);
        const float fsc = __builtin_amdgcn_exp2f(m - mn);
        m = mn;
        l *= fsc;
#pragma unroll
        for (int dt = 0; dt < 2; ++dt)
#pragma unroll
          for (int r = 0; r < 4; ++r) oa[dt][r] *= fsc;
      }
      float p[4][4];
      float psum = 0.f;
#pragma unroll
      for (int mt = 0; mt < 4; ++mt)
#pragma unroll
        for (int r = 0; r < 4; ++r) {
          p[mt][r] = __builtin_amdgcn_exp2f(s4[mt][r] - m);
          psum += p[mt][r];
        }
      psum += __shfl_xor(psum, 16);
      psum += __shfl_xor(psum, 32);
      l += psum;

      // P -> per-wave LDS (packed cvt, b64 writes), then read B-frags (b128)
#pragma unroll
      for (int mt = 0; mt < 4; ++mt) {
        union { fp16x2 h2[2]; uint2 u2; } pw;
        pw.h2[0] = __builtin_amdgcn_cvt_pkrtz(p[mt][0], p[mt][1]);
        pw.h2[1] = __builtin_amdgcn_cvt_pkrtz(p[mt][2], p[mt][3]);
        *(uint2*)&pl[wid][lo][16 * mt + 4 * g] = pw.u2;
      }
#pragma unroll
      for (int c2 = 0; c2 < 2; ++c2) {
        const f16x8 pbv = *(const f16x8*)&pl[wid][lo][c2 * 32 + 8 * g];
#pragma unroll
        for (int dt = 0; dt < 2; ++dt) {
          const f16x8 vf = *(const f16x8*)&vt[buf][dt * 16 + lo][c2 * 32 + 8 * g];
          oa[dt] = __builtin_amdgcn_mfma_f32_16x16x32_f16(vf, pbv, oa[dt], 0, 0, 0);
        }
      }

      // carry prefetched regs into next iter
#pragma unroll
      for (int dd = 0; dd < 4; ++dd) ka[dd] = ka2[dd];
      va = va2;
    }
  }

  // epilogue: store chunk-normalized O (f16) + m,l
  const float invL = 1.f / l;
  const size_t ob = (size_t)(chunk * BH + bh) * HD * T;
#pragma unroll
  for (int dt = 0; dt < 2; ++dt)
#pragma unroll
    for (int r = 0; r < 4; ++r)
      opart[ob + (size_t)(dt * 16 + 4 * g + r) * T + tq] =
          (_Float16)(oa[dt][r] * invL);
  if (g == 0) {
    const size_t pb = (size_t)(chunk * BH + bh) * T + tq;
    mpart[pb] = m;
    lpart[pb] = l;
  }
}

// Combine chunk partials + remove component along normalized v (fp16 cast
// points). 4-way d-split: lane = (q&15) | dgrp<<4, each thread handles 8 of
// 32 d-values; norm^2 and o.vhat dots wave-reduced via shfl_xor(16/32).
__global__ __launch_bounds__(256)
void attn_combine(const _Float16* __restrict__ opart, const float* __restrict__ mpart,
                  const float* __restrict__ lpart, const _Float16* __restrict__ qkv,
                  _Float16* __restrict__ AOh)
{
  const int lane = threadIdx.x & 63;
  const int wv_  = threadIdx.x >> 6;   // wave in block: 0..3
  const int ql   = lane & 15;
  const int dgrp = lane >> 4;          // 0..3
  const int d0   = dgrp * 8;
  const int q  = blockIdx.x * 64 + wv_ * 16 + ql;
  const int bh = blockIdx.y;
  const int b  = bh >> 3, h = bh & 7;

  float mv[NCHUNK], lv[NCHUNK];
  float M = -1e30f;
#pragma unroll
  for (int c = 0; c < NCHUNK; ++c) {
    const size_t pb = (size_t)(c * BH + bh) * T + q;
    mv[c] = mpart[pb];
    lv[c] = lpart[pb];
    M = fmaxf(M, mv[c]);
  }
  float L = 0.f;
  float wc[NCHUNK];
#pragma unroll
  for (int c = 0; c < NCHUNK; ++c) {
    wc[c] = __builtin_amdgcn_exp2f(mv[c] - M) * lv[c];
    L += wc[c];
  }
  const float inv = 1.f / L;
#pragma unroll
  for (int c = 0; c < NCHUNK; ++c) wc[c] *= inv;

  float o[8];
#pragma unroll
  for (int j = 0; j < 8; ++j) o[j] = 0.f;
#pragma unroll
  for (int c = 0; c < NCHUNK; ++c) {
    const size_t ob = (size_t)(c * BH + bh) * HD * T + q;
#pragma unroll
    for (int j = 0; j < 8; ++j)
      o[j] = fmaf(wc[c], (float)opart[ob + (size_t)(d0 + j) * T], o[j]);
  }

  const size_t vbase = ((size_t)b * 3 * C + 2 * C + h * HD) * T + q;
  float vv[8], n2 = 0.f;
#pragma unroll
  for (int j = 0; j < 8; ++j) {
    vv[j] = (float)qkv[vbase + (size_t)(d0 + j) * T];
    n2 = fmaf(vv[j], vv[j], n2);
  }
  n2 += __shfl_xor(n2, 16);
  n2 += __shfl_xor(n2, 32);
  const float nrm = fmaxf(sqrtf(n2), 1e-12f);
  float dot = 0.f;
  float o16[8], vn[8];
#pragma unroll
  for (int j = 0; j < 8; ++j) {
    o16[j] = (float)(_Float16)(o[j]);
    vn[j]  = (float)(_Float16)(vv[j] / nrm);
    dot = fmaf(o16[j], vn[j], dot);
  }
  dot += __shfl_xor(dot, 16);
  dot += __shfl_xor(dot, 32);
  const size_t ab = ((size_t)b * C + h * HD) * T + q;
#pragma unroll
  for (int j = 0; j < 8; ++j)
    AOh[ab + (size_t)(d0 + j) * T] = (_Float16)(o16[j] - dot * vn[j]);
}

__global__ __launch_bounds__(256)
void gn_norm(const float* __restrict__ Y, const float* __restrict__ stats,
             const float* __restrict__ gamma, const float* __restrict__ beta,
             float* __restrict__ O)
{
  const int i = blockIdx.x * 256 + threadIdx.x;
  const int b = i / (C * T);
  const int c = (i / T) & (C - 1);
  const float mu  = stats[b * 2] * INV_N;
  const float var = stats[b * 2 + 1] * INV_N - mu * mu;
  const float r = rsqrtf(var + 1e-5f);
  O[i] = (Y[i] - mu) * r * gamma[c] + beta[c];
}

extern "C" void kernel_launch(void* const* d_in, const int* in_sizes, int n_in,
                              void* d_out, int out_size, void* d_ws, size_t ws_size,
                              hipStream_t stream)
{
  const float* x      = (const float*)d_in[0];
  const float* wq     = (const float*)d_in[1];
  const float* bq     = (const float*)d_in[2];
  const float* wk     = (const float*)d_in[3];
  const float* bk     = (const float*)d_in[4];
  const float* wv     = (const float*)d_in[5];
  const float* bv     = (const float*)d_in[6];
  const float* wo     = (const float*)d_in[7];
  const float* bo     = (const float*)d_in[8];
  const float* gamma1 = (const float*)d_in[9];
  const float* beta1  = (const float*)d_in[10];
  const float* w1     = (const float*)d_in[11];
  const float* bf1    = (const float*)d_in[12];
  const float* w2     = (const float*)d_in[13];
  const float* bf2    = (const float*)d_in[14];
  const float* gamma2 = (const float*)d_in[15];
  const float* beta2  = (const float*)d_in[16];

  char* ws = (char*)d_ws;
  _Float16* qkv16 = (_Float16*)(ws + OFF_QKV);
  _Float16* ao16  = (_Float16*)(ws + OFF_AO);
  float*    x1    = (float*)(ws + OFF_X1);
  _Float16* opart = (_Float16*)(ws + OFF_OP);
  float*    mpart = (float*)(ws + OFF_MP);
  float*    lpart = (float*)(ws + OFF_LP);
  _Float16* h16   = (_Float16*)(ws + OFF_H16);
  _Float16* w16   = (_Float16*)(ws + OFF_W16);
  float*    bqkv  = (float*)(ws + OFF_BQKV);
  float*    stats = (float*)(ws + OFF_STATS);
  float*    out   = (float*)d_out;

  const _Float16* wqkv16 = w16;
  const _Float16* wo16   = w16 + N_WQKV;
  const _Float16* w116   = w16 + N_WQKV + N_WO;
  const _Float16* w216   = w16 + N_WQKV + N_WO + N_W1;

  const dim3 blk256(256);

  convert_weights<<<768, blk256, 0, stream>>>(wq, wk, wv, wo, w1, w2, bq, bk, bv,
                                              w16, bqkv, stats);

  // Fused QKV projection: CO=768, K=256, fp32 x in, f16 out
  gemm_mfma<false, false, false, false, false, float, _Float16>
      <<<dim3(36, 12, 2), blk256, 0, stream>>>(
          wqkv16, x, bqkv, nullptr, qkv16, 3 * C, C, nullptr, nullptr, nullptr, nullptr);

  // Flash attention partials (4-way key split, 8-wave blocks) + combine
  attn_mfma<<<dim3(T / 128, NCHUNK, BH), dim3(512), 0, stream>>>(qkv16, opart, mpart, lpart);
  attn_combine<<<dim3(T / 64, BH), blk256, 0, stream>>>(opart, mpart, lpart, qkv16, ao16);

  // Output projection + residual -> x1 raw; fused GN1 stats
  gemm_mfma<false, true, false, false, true, _Float16, float>
      <<<dim3(36, 4, 2), blk256, 0, stream>>>(
          wo16, ao16, bo, x, x1, C, C, nullptr, nullptr, nullptr, stats);

  // FFN1: GN1 applied to staged input, ReLU, f16 out
  gemm_mfma<true, false, true, false, false, float, _Float16>
      <<<dim3(36, 16, 2), blk256, 0, stream>>>(
          w116, x1, bf1, nullptr, h16, F, C, stats, gamma1, beta1, nullptr);

  // FFN2: + GN1(x1raw) residual -> d_out raw; fused GN2 stats
  gemm_mfma<false, true, false, true, true, _Float16, float>
      <<<dim3(36, 4, 2), blk256, 0, stream>>>(
          w216, h16, bf2, x1, out, C, F, stats, gamma1, beta1, stats + 4);

  // GN2 normalize in place on d_out
  gn_norm<<<dim3(4608), blk256, 0, stream>>>(out, stats + 4, gamma2, beta2, out);
}